// Round 7
// baseline (318.584 us; speedup 1.0000x reference)
//
#include <hip/hip_runtime.h>
#include <hip/hip_cooperative_groups.h>

namespace cg = cooperative_groups;

#define B 16
#define L 2048
#define D 512
#define MAXC 1025  // L/2 + 1
#define NBLK 1024  // 4 blocks/CU on 256 CUs: co-residency guaranteed
#define NTHR 256

// ===========================================================================
// Fused cooperative kernel: phase1 weights -> grid.sync -> phase2 segments
// -> grid.sync -> phase3 pool.
// ===========================================================================
__global__ __launch_bounds__(NTHR, 4) void k_fused(
    const float* __restrict__ xs, const float* __restrict__ w_lin,
    const float* __restrict__ b_lin, const int* __restrict__ olens,
    float* __restrict__ out, float* __restrict__ olens_out,
    float* __restrict__ w_buf, int* __restrict__ starts,
    int* __restrict__ ends, int* __restrict__ count)
{
    cg::grid_group grid = cg::this_grid();
    const int tid = threadIdx.x;
    const int wave = tid >> 6;
    const int lane = tid & 63;

    // ---------------- phase 1: w[row] = sigmoid(xs[row,:].w_lin + b) --------
    {
        const float4* wl4 = (const float4*)w_lin;
        const float4 c0 = wl4[lane];        // hoisted: loaded once per thread
        const float4 c1 = wl4[lane + 64];
        const float bias = b_lin[0];
        const int gw = blockIdx.x * 4 + wave;  // 4096 waves; 32768 rows total
        #pragma unroll
        for (int it = 0; it < 8; ++it) {
            const int row = gw + 4096 * it;
            const float4* x4 = (const float4*)(xs + (size_t)row * D);
            float4 a0 = x4[lane];
            float4 a1 = x4[lane + 64];
            float p = a0.x * c0.x + a0.y * c0.y + a0.z * c0.z + a0.w * c0.w
                    + a1.x * c1.x + a1.y * c1.y + a1.z * c1.z + a1.w * c1.w;
            #pragma unroll
            for (int off = 32; off > 0; off >>= 1) p += __shfl_xor(p, off, 64);
            if (lane == 0) w_buf[row] = 1.0f / (1.0f + expf(-(p + bias)));
        }
    }

    grid.sync();

    // ---------------- phase 2: strict minima -> segment lists (blocks 0..B-1)
    __shared__ int scn[NTHR];
    if (blockIdx.x < B) {
        const int b = blockIdx.x;
        const float* wb = w_buf + (size_t)b * L;

        int pos[4];
        int lcnt = 0;
        const int t0 = tid * 8;
        #pragma unroll
        for (int i = 0; i < 8; ++i) {
            int t = t0 + i;
            if (t >= 1 && t <= L - 2) {
                float c = wb[t];
                if (c < wb[t - 1] && c < wb[t + 1]) pos[lcnt++] = t;
            }
        }

        scn[tid] = lcnt;
        __syncthreads();
        #pragma unroll
        for (int s = 1; s < NTHR; s <<= 1) {
            int v = (tid >= s) ? scn[tid - s] : 0;
            __syncthreads();
            scn[tid] += v;
            __syncthreads();
        }
        const int excl = scn[tid] - lcnt;
        const int total = scn[NTHR - 1];

        for (int i = 0; i < lcnt; ++i) {
            int j = excl + i;
            int t = pos[i];
            starts[b * MAXC + j + 1] = t;
            int e = t + 2;
            ends[b * MAXC + j] = (e < L) ? e : L;
        }
        if (tid == 0) {
            starts[b * MAXC + 0] = 0;
            ends[b * MAXC + total] = L;
            count[b] = total + 1;
            // stored as float32 NUMBER (harness decodes d_out uniformly as f32)
            int v = (int)((float)olens[b] / (float)olens[0] * (float)MAXC);
            olens_out[b] = (float)v;
        }
    }

    grid.sync();

    // ---------------- phase 3: segmented weighted pool ----------------------
    {
        const int sub = tid >> 7;      // two 128-thread groups per block
        const int st  = tid & 127;
        for (int r = blockIdx.x * 2 + sub; r < B * MAXC; r += NBLK * 2) {
            const int b = r / MAXC;
            const int m = r - b * MAXC;
            float4* out4 = (float4*)(out + (size_t)r * D);

            if (m >= count[b]) {
                out4[st] = make_float4(0.f, 0.f, 0.f, 0.f);
                continue;
            }

            const int s = starts[b * MAXC + m];
            const int e = ends[b * MAXC + m];
            const float* wb = w_buf + (size_t)b * L;
            const float4* x4 = (const float4*)(xs + (size_t)b * L * D);

            float4 acc = make_float4(0.f, 0.f, 0.f, 0.f);
            float dsum = 0.f;
            for (int t = s; t < e; ++t) {
                float wt = wb[t];
                dsum += wt;
                float4 x = x4[(size_t)t * (D / 4) + st];
                acc.x += x.x * wt;
                acc.y += x.y * wt;
                acc.z += x.z * wt;
                acc.w += x.w * wt;
            }
            float inv = 1.0f / fmaxf(dsum, 1e-6f);
            out4[st] = make_float4(acc.x * inv, acc.y * inv, acc.z * inv, acc.w * inv);
        }
    }
}

// ===========================================================================
// Fallback path (proven Round-4 code): 3 separate kernels, no grid sync.
// ===========================================================================
__global__ __launch_bounds__(256) void k_weights(const float* __restrict__ xs,
                                                 const float* __restrict__ w_lin,
                                                 const float* __restrict__ b_lin,
                                                 float* __restrict__ w_out) {
    const int wave = threadIdx.x >> 6;
    const int lane = threadIdx.x & 63;
    const int row = blockIdx.x * 4 + wave;
    if (row >= B * L) return;

    const float4* x4  = (const float4*)(xs + (size_t)row * D);
    const float4* wl4 = (const float4*)w_lin;

    float4 a0 = x4[lane];
    float4 c0 = wl4[lane];
    float p = a0.x * c0.x + a0.y * c0.y + a0.z * c0.z + a0.w * c0.w;
    float4 a1 = x4[lane + 64];
    float4 c1 = wl4[lane + 64];
    p += a1.x * c1.x + a1.y * c1.y + a1.z * c1.z + a1.w * c1.w;

    #pragma unroll
    for (int off = 32; off > 0; off >>= 1) p += __shfl_xor(p, off, 64);

    if (lane == 0) {
        float z = p + b_lin[0];
        w_out[row] = 1.0f / (1.0f + expf(-z));
    }
}

__global__ __launch_bounds__(256) void k_segments(const float* __restrict__ w,
                                                  int* __restrict__ starts,
                                                  int* __restrict__ ends,
                                                  int* __restrict__ count,
                                                  const int* __restrict__ olens,
                                                  float* __restrict__ olens_out) {
    const int b = blockIdx.x;
    const int tid = threadIdx.x;
    const float* wb = w + (size_t)b * L;

    int pos[4];
    int lcnt = 0;
    const int t0 = tid * 8;
    #pragma unroll
    for (int i = 0; i < 8; ++i) {
        int t = t0 + i;
        if (t >= 1 && t <= L - 2) {
            float c = wb[t];
            if (c < wb[t - 1] && c < wb[t + 1]) pos[lcnt++] = t;
        }
    }

    __shared__ int scn[256];
    scn[tid] = lcnt;
    __syncthreads();
    #pragma unroll
    for (int s = 1; s < 256; s <<= 1) {
        int v = (tid >= s) ? scn[tid - s] : 0;
        __syncthreads();
        scn[tid] += v;
        __syncthreads();
    }
    const int excl = scn[tid] - lcnt;
    const int total = scn[255];

    for (int i = 0; i < lcnt; ++i) {
        int j = excl + i;
        int t = pos[i];
        starts[b * MAXC + j + 1] = t;
        int e = t + 2;
        ends[b * MAXC + j] = (e < L) ? e : L;
    }
    if (tid == 0) {
        starts[b * MAXC + 0] = 0;
        ends[b * MAXC + total] = L;
        count[b] = total + 1;
        int v = (int)((float)olens[b] / (float)olens[0] * (float)MAXC);
        olens_out[b] = (float)v;
    }
}

__global__ __launch_bounds__(128) void k_pool(const float* __restrict__ xs,
                                              const float* __restrict__ w,
                                              const int* __restrict__ starts,
                                              const int* __restrict__ ends,
                                              const int* __restrict__ count,
                                              float* __restrict__ out) {
    const int m = blockIdx.x;
    const int b = blockIdx.y;
    const int tid = threadIdx.x;

    float4* out4 = (float4*)(out + (size_t)(b * MAXC + m) * D);

    if (m >= count[b]) {
        out4[tid] = make_float4(0.f, 0.f, 0.f, 0.f);
        return;
    }

    const int s = starts[b * MAXC + m];
    const int e = ends[b * MAXC + m];
    const float* wb = w + (size_t)b * L;
    const float4* x4 = (const float4*)(xs + (size_t)b * L * D);

    float4 acc = make_float4(0.f, 0.f, 0.f, 0.f);
    float dsum = 0.f;
    for (int t = s; t < e; ++t) {
        float wt = wb[t];
        dsum += wt;
        float4 x = x4[(size_t)t * (D / 4) + tid];
        acc.x += x.x * wt;
        acc.y += x.y * wt;
        acc.z += x.z * wt;
        acc.w += x.w * wt;
    }
    float inv = 1.0f / fmaxf(dsum, 1e-6f);
    out4[tid] = make_float4(acc.x * inv, acc.y * inv, acc.z * inv, acc.w * inv);
}

// ---------------------------------------------------------------------------
extern "C" void kernel_launch(void* const* d_in, const int* in_sizes, int n_in,
                              void* d_out, int out_size, void* d_ws, size_t ws_size,
                              hipStream_t stream) {
    const float* xs    = (const float*)d_in[0];
    const float* w_lin = (const float*)d_in[1];
    const float* b_lin = (const float*)d_in[2];
    const int*   olens = (const int*)d_in[3];

    float* out = (float*)d_out;
    float* olens_out = (float*)d_out + (size_t)B * MAXC * D;  // f32 values, tuple tail

    char* ws = (char*)d_ws;
    float* w_buf = (float*)ws;                                  // B*L floats
    int* starts  = (int*)(ws + (size_t)B * L * sizeof(float));  // B*MAXC
    int* ends    = starts + B * MAXC;                           // B*MAXC
    int* count   = ends + B * MAXC;                             // B

    void* args[] = {
        (void*)&xs, (void*)&w_lin, (void*)&b_lin, (void*)&olens,
        (void*)&out, (void*)&olens_out, (void*)&w_buf,
        (void*)&starts, (void*)&ends, (void*)&count
    };
    hipError_t err = hipLaunchCooperativeKernel((const void*)k_fused, dim3(NBLK),
                                                dim3(NTHR), args, 0, stream);
    if (err != hipSuccess) {
        // Deterministic fallback: same work, 3 proven kernels (Round-4 pass).
        k_weights<<<dim3((B * L) / 4), 256, 0, stream>>>(xs, w_lin, b_lin, w_buf);
        k_segments<<<dim3(B), 256, 0, stream>>>(w_buf, starts, ends, count, olens, olens_out);
        k_pool<<<dim3(MAXC, B), 128, 0, stream>>>(xs, w_buf, starts, ends, count, out);
    }
}

// Round 8
// 119.030 us; speedup vs baseline: 2.6765x; 2.6765x over previous
//
#include <hip/hip_runtime.h>

#define B 16
#define L 2048
#define D 512
#define MAXC 1025  // L/2 + 1

// NOTE (R7 post-mortem): cooperative grid.sync() fusion measured 218 us for
// the same work these 3 kernels do in ~35 us — ROCm grid sync spin across
// 8 XCDs dominates. Keep separate launches; graph-captured launch gaps are ~us.

// ---------------------------------------------------------------------------
// K1: w[row] = sigmoid(dot(xs[row,:], w_lin) + b0), row in [0, B*L)
// One 64-lane wave per row; each lane loads 2 x float4 (covers 512 floats).
// ---------------------------------------------------------------------------
__global__ __launch_bounds__(256) void k_weights(const float* __restrict__ xs,
                                                 const float* __restrict__ w_lin,
                                                 const float* __restrict__ b_lin,
                                                 float* __restrict__ w_out) {
    const int wave = threadIdx.x >> 6;
    const int lane = threadIdx.x & 63;
    const int row = blockIdx.x * 4 + wave;
    if (row >= B * L) return;

    const float4* x4  = (const float4*)(xs + (size_t)row * D);
    const float4* wl4 = (const float4*)w_lin;

    float4 a0 = x4[lane];
    float4 c0 = wl4[lane];
    float p = a0.x * c0.x + a0.y * c0.y + a0.z * c0.z + a0.w * c0.w;
    float4 a1 = x4[lane + 64];
    float4 c1 = wl4[lane + 64];
    p += a1.x * c1.x + a1.y * c1.y + a1.z * c1.z + a1.w * c1.w;

    // 64-lane butterfly reduce
    #pragma unroll
    for (int off = 32; off > 0; off >>= 1) p += __shfl_xor(p, off, 64);

    if (lane == 0) {
        float z = p + b_lin[0];
        w_out[row] = 1.0f / (1.0f + expf(-z));
    }
}

// ---------------------------------------------------------------------------
// K2: per batch, find strict local minima of w[b,:], build segment lists.
//   starts = [0, m_1, ..., m_k]; ends = [m_1+2, ..., m_k+2, L]; count = k+1
// ---------------------------------------------------------------------------
__global__ __launch_bounds__(256) void k_segments(const float* __restrict__ w,
                                                  int* __restrict__ starts,
                                                  int* __restrict__ ends,
                                                  int* __restrict__ count,
                                                  const int* __restrict__ olens,
                                                  float* __restrict__ olens_out) {
    const int b = blockIdx.x;
    const int tid = threadIdx.x;
    const float* wb = w + (size_t)b * L;

    int pos[4];
    int lcnt = 0;
    const int t0 = tid * 8;
    #pragma unroll
    for (int i = 0; i < 8; ++i) {
        int t = t0 + i;
        if (t >= 1 && t <= L - 2) {
            float c = wb[t];
            if (c < wb[t - 1] && c < wb[t + 1]) pos[lcnt++] = t;
        }
    }

    __shared__ int scn[256];
    scn[tid] = lcnt;
    __syncthreads();
    #pragma unroll
    for (int s = 1; s < 256; s <<= 1) {
        int v = (tid >= s) ? scn[tid - s] : 0;
        __syncthreads();
        scn[tid] += v;
        __syncthreads();
    }
    const int excl = scn[tid] - lcnt;
    const int total = scn[255];

    for (int i = 0; i < lcnt; ++i) {
        int j = excl + i;
        int t = pos[i];
        starts[b * MAXC + j + 1] = t;
        int e = t + 2;
        ends[b * MAXC + j] = (e < L) ? e : L;
    }
    if (tid == 0) {
        starts[b * MAXC + 0] = 0;
        ends[b * MAXC + total] = L;
        count[b] = total + 1;
        // stored as float32 NUMBER (harness decodes d_out uniformly as f32)
        int v = (int)((float)olens[b] / (float)olens[0] * (float)MAXC);
        olens_out[b] = (float)v;
    }
}

// ---------------------------------------------------------------------------
// K3: 256-thread block handles TWO output rows (two 128-thread groups).
// Pool xs*w over [start, end); rows m >= count[b] write exact zeros.
// ---------------------------------------------------------------------------
__global__ __launch_bounds__(256) void k_pool(const float* __restrict__ xs,
                                              const float* __restrict__ w,
                                              const int* __restrict__ starts,
                                              const int* __restrict__ ends,
                                              const int* __restrict__ count,
                                              float* __restrict__ out) {
    const int sub = threadIdx.x >> 7;   // which of the 2 rows
    const int st  = threadIdx.x & 127;  // lane within the 128-thread group
    const int r = blockIdx.x * 2 + sub; // global output row
    if (r >= B * MAXC) return;
    const int b = r / MAXC;
    const int m = r - b * MAXC;

    float4* out4 = (float4*)(out + (size_t)r * D);

    if (m >= count[b]) {
        out4[st] = make_float4(0.f, 0.f, 0.f, 0.f);
        return;
    }

    const int s = starts[b * MAXC + m];
    const int e = ends[b * MAXC + m];
    const float* wb = w + (size_t)b * L;
    const float4* x4 = (const float4*)(xs + (size_t)b * L * D);

    float4 acc = make_float4(0.f, 0.f, 0.f, 0.f);
    float dsum = 0.f;
    #pragma unroll 2
    for (int t = s; t < e; ++t) {
        float wt = wb[t];  // same addr across lanes -> broadcast
        dsum += wt;
        float4 x = x4[(size_t)t * (D / 4) + st];
        acc.x += x.x * wt;
        acc.y += x.y * wt;
        acc.z += x.z * wt;
        acc.w += x.w * wt;
    }
    float inv = 1.0f / fmaxf(dsum, 1e-6f);
    out4[st] = make_float4(acc.x * inv, acc.y * inv, acc.z * inv, acc.w * inv);
}

// ---------------------------------------------------------------------------
extern "C" void kernel_launch(void* const* d_in, const int* in_sizes, int n_in,
                              void* d_out, int out_size, void* d_ws, size_t ws_size,
                              hipStream_t stream) {
    const float* xs    = (const float*)d_in[0];
    const float* w_lin = (const float*)d_in[1];
    const float* b_lin = (const float*)d_in[2];
    const int*   olens = (const int*)d_in[3];

    float* out = (float*)d_out;
    float* olens_out = (float*)d_out + (size_t)B * MAXC * D;  // f32 values, tuple tail

    char* ws = (char*)d_ws;
    float* w_buf = (float*)ws;                                  // B*L floats
    int* starts  = (int*)(ws + (size_t)B * L * sizeof(float));  // B*MAXC
    int* ends    = starts + B * MAXC;                           // B*MAXC
    int* count   = ends + B * MAXC;                             // B

    k_weights<<<dim3((B * L) / 4), 256, 0, stream>>>(xs, w_lin, b_lin, w_buf);
    k_segments<<<dim3(B), 256, 0, stream>>>(w_buf, starts, ends, count, olens, olens_out);
    const int nrows = B * MAXC;  // 16400
    k_pool<<<dim3((nrows + 1) / 2), 256, 0, stream>>>(xs, w_buf, starts, ends, count, out);
}